// Round 1
// 1413.669 us; speedup vs baseline: 1.0437x; 1.0437x over previous
//
#include <hip/hip_runtime.h>
#include <hip/hip_bf16.h>
#include <stdint.h>

#define D 128
#define NNODES 100000
#define NEDGES 800000
#define LDSTR 136   // bf16 h-tile row stride (128 + 8 pad)
#define EFSTR 132   // f32 epilogue tile row stride (64 rows x 132 f32 = 33792 B <= Hs)

typedef __bf16 bf16_t;
typedef bf16_t bf16x8 __attribute__((ext_vector_type(8)));
typedef float  f32x4  __attribute__((ext_vector_type(4)));

// ---- weight transpose+convert: dst[n*K + k] = (bf16) src[k*N + n]  (dst = W^T, row-major [N][K])
__global__ void wprep_kernel(const float* __restrict__ src, bf16_t* __restrict__ dst,
                             int K, int N) {
  int idx = blockIdx.x * blockDim.x + threadIdx.x;
  if (idx >= K * N) return;
  int n = idx / K;
  int k = idx - n * K;
  dst[idx] = (bf16_t)src[(size_t)k * N + n];
}

// One K=128 chunk of GEMM1 with A-fragments loaded DIRECTLY from global memory.
// AP[i] points at the source row for fragment rows m0+i*16+ln; per-lane 32 B
// (8 consecutive f32 at k = kk + q*8) is exactly one MFMA A-fragment.
#define MFMA_CHUNK(AP, WPTR, WS, CB) do {                                        \
    _Pragma("unroll")                                                            \
    for (int kk = 0; kk < 128; kk += 32) {                                       \
      bf16x8 a[4], bb[4];                                                        \
      _Pragma("unroll")                                                          \
      for (int i = 0; i < 4; ++i) {                                              \
        float4 f0 = *(const float4*)((AP)[i] + kk + q * 8);                      \
        float4 f1 = *(const float4*)((AP)[i] + kk + q * 8 + 4);                  \
        a[i] = (bf16x8){(bf16_t)f0.x, (bf16_t)f0.y, (bf16_t)f0.z, (bf16_t)f0.w, \
                        (bf16_t)f1.x, (bf16_t)f1.y, (bf16_t)f1.z, (bf16_t)f1.w};\
      }                                                                          \
      const int kg = (CB) + kk + q * 8;                                          \
      _Pragma("unroll")                                                          \
      for (int j = 0; j < 4; ++j)                                                \
        bb[j] = *(const bf16x8*)&(WPTR)[(size_t)(n0 + j * 16 + ln) * (WS) + kg]; \
      _Pragma("unroll")                                                          \
      for (int i = 0; i < 4; ++i)                                                \
        _Pragma("unroll")                                                        \
        for (int j = 0; j < 4; ++j)                                              \
          acc[i][j] = __builtin_amdgcn_mfma_f32_16x16x32_bf16(a[i], bb[j],       \
                                                              acc[i][j], 0, 0, 0);\
    }                                                                            \
  } while (0)

// ============================ EDGE KERNEL ============================
__global__ __launch_bounds__(256, 3) void edge_kernel(
    const float* __restrict__ node_f, const float* __restrict__ edge_f,
    const int* __restrict__ senders, const int* __restrict__ receivers,
    const bf16_t* __restrict__ W1T,   // [128][384] bf16 (We1^T)
    const float* __restrict__ be1,
    const bf16_t* __restrict__ W2T,   // [128][128] bf16 (We2^T)
    const float* __restrict__ be2,
    float* __restrict__ agg,          // [NNODES][128] f32 (pre-zeroed)
    float* __restrict__ out_edges)    // [NEDGES][128] f32
{
  __shared__ __align__(16) bf16_t Hs[128 * LDSTR];

  const int tid  = threadIdx.x;
  const int base = blockIdx.x * 128;
  const int lane = tid & 63;
  const int wave = tid >> 6;
  const int q    = lane >> 4;
  const int ln   = lane & 15;
  const int m0   = (wave & 1) * 64;
  const int n0   = (wave >> 1) * 64;

  // Per-fragment gathered row pointers (no LDS, no barriers in GEMM1)
  const float* apA[4];
  const float* apB[4];
  const float* apC[4];
  #pragma unroll
  for (int i = 0; i < 4; ++i) {
    const int row = base + m0 + i * 16 + ln;
    apA[i] = node_f + (size_t)senders[row]   * D;
    apB[i] = node_f + (size_t)receivers[row] * D;
    apC[i] = edge_f + (size_t)row            * D;
  }

  f32x4 acc[4][4];
  #pragma unroll
  for (int i = 0; i < 4; i++)
    #pragma unroll
    for (int j = 0; j < 4; j++) acc[i][j] = {0.f, 0.f, 0.f, 0.f};

  // ---- GEMM1: 3 K-chunks, A direct from global (same accumulation order as before) ----
  MFMA_CHUNK(apA, W1T, 384, 0);
  MFMA_CHUNK(apB, W1T, 384, 128);
  MFMA_CHUNK(apC, W1T, 384, 256);

  // ---- h = relu(acc + be1) -> Hs (bf16) ----
  #pragma unroll
  for (int i = 0; i < 4; i++)
    #pragma unroll
    for (int j = 0; j < 4; j++)
      #pragma unroll
      for (int r = 0; r < 4; r++) {
        int row = m0 + i * 16 + q * 4 + r;
        int col = n0 + j * 16 + ln;
        float v = acc[i][j][r] + be1[col];
        Hs[row * LDSTR + col] = (bf16_t)fmaxf(v, 0.f);
      }
  __syncthreads();

  // ---- GEMM2: e_upd = h @ We2 (K=128) ----
  f32x4 acc2[4][4];
  #pragma unroll
  for (int i = 0; i < 4; i++)
    #pragma unroll
    for (int j = 0; j < 4; j++) acc2[i][j] = {0.f, 0.f, 0.f, 0.f};

  #pragma unroll
  for (int kk = 0; kk < 128; kk += 32) {
    bf16x8 a[4], bb[4];
    #pragma unroll
    for (int i = 0; i < 4; i++)
      a[i] = *(const bf16x8*)&Hs[(m0 + i * 16 + ln) * LDSTR + kk + q * 8];
    #pragma unroll
    for (int j = 0; j < 4; j++)
      bb[j] = *(const bf16x8*)&W2T[(size_t)(n0 + j * 16 + ln) * 128 + kk + q * 8];
    #pragma unroll
    for (int i = 0; i < 4; i++)
      #pragma unroll
      for (int j = 0; j < 4; j++)
        acc2[i][j] = __builtin_amdgcn_mfma_f32_16x16x32_bf16(a[i], bb[j], acc2[i][j], 0, 0, 0);
  }

  // ---- epilogue part 1: +be2, atomic scatter from register (MFMA) layout ----
  float be2v[4];
  #pragma unroll
  for (int j = 0; j < 4; ++j) be2v[j] = be2[n0 + j * 16 + ln];

  int rq[4][4];
  #pragma unroll
  for (int i = 0; i < 4; ++i)
    #pragma unroll
    for (int r = 0; r < 4; ++r)
      rq[i][r] = receivers[base + m0 + i * 16 + q * 4 + r];

  #pragma unroll
  for (int i = 0; i < 4; i++)
    #pragma unroll
    for (int j = 0; j < 4; j++)
      #pragma unroll
      for (int r = 0; r < 4; r++) {
        float v = acc2[i][j][r] + be2v[j];
        acc2[i][j][r] = v;
        unsafeAtomicAdd(&agg[(size_t)rq[i][r] * D + n0 + j * 16 + ln], v);
      }

  // ---- epilogue part 2: vectorized residual via f32 LDS transpose (2 half-tiles) ----
  float* Ef = (float*)Hs;
  const int lr = tid >> 2;          // 0..63
  const int cb = (tid & 3) * 32;    // 0,32,64,96
  #pragma unroll
  for (int half = 0; half < 2; ++half) {
    __syncthreads();                // prior Hs/Ef reads complete
    if (m0 == half * 64) {
      #pragma unroll
      for (int i = 0; i < 4; i++)
        #pragma unroll
        for (int j = 0; j < 4; j++)
          #pragma unroll
          for (int r = 0; r < 4; r++)
            Ef[(i * 16 + q * 4 + r) * EFSTR + n0 + j * 16 + ln] = acc2[i][j][r];
    }
    __syncthreads();
    const size_t grow = (size_t)(base + half * 64 + lr);
    const float4* ep = (const float4*)(edge_f + grow * D + cb);
    float4*       op = (float4*)(out_edges + grow * D + cb);
    #pragma unroll
    for (int t = 0; t < 8; ++t) {
      float4 e = ep[t];
      float4 v = *(const float4*)&Ef[lr * EFSTR + cb + 4 * t];
      float4 o;
      o.x = e.x + v.x; o.y = e.y + v.y; o.z = e.z + v.z; o.w = e.w + v.w;
      op[t] = o;
    }
  }
}

// ============================ NODE KERNEL ============================
__global__ __launch_bounds__(256, 3) void node_kernel(
    const float* __restrict__ node_f,
    const bf16_t* __restrict__ W1T,   // [128][256] bf16 (Wn1^T)
    const float* __restrict__ b1,
    const bf16_t* __restrict__ W2T,   // [128][128] bf16 (Wn2^T)
    const float* __restrict__ b2,
    const float* __restrict__ agg,    // d_out node region (read)
    float* __restrict__ out_nodes)    // same region (write — per-block row ownership)
{
  __shared__ __align__(16) bf16_t Hs[128 * LDSTR];

  const int tid    = threadIdx.x;
  const int base   = blockIdx.x * 128;
  const int nvalid = min(128, NNODES - base);

  const int lane = tid & 63;
  const int wave = tid >> 6;
  const int q    = lane >> 4;
  const int ln   = lane & 15;
  const int m0   = (wave & 1) * 64;
  const int n0   = (wave >> 1) * 64;

  const float* apA[4];
  const float* apB[4];
  #pragma unroll
  for (int i = 0; i < 4; ++i) {
    const size_t row = (size_t)(base + min(m0 + i * 16 + ln, nvalid - 1));
    apA[i] = node_f + row * D;
    apB[i] = agg    + row * D;
  }

  f32x4 acc[4][4];
  #pragma unroll
  for (int i = 0; i < 4; i++)
    #pragma unroll
    for (int j = 0; j < 4; j++) acc[i][j] = {0.f, 0.f, 0.f, 0.f};

  // ---- GEMM1: [node | agg] @ Wn1, A direct from global ----
  MFMA_CHUNK(apA, W1T, 256, 0);
  MFMA_CHUNK(apB, W1T, 256, 128);

  // ---- h = relu(acc + b1) -> Hs ----
  #pragma unroll
  for (int i = 0; i < 4; i++)
    #pragma unroll
    for (int j = 0; j < 4; j++)
      #pragma unroll
      for (int r = 0; r < 4; r++) {
        int row = m0 + i * 16 + q * 4 + r;
        int col = n0 + j * 16 + ln;
        float v = acc[i][j][r] + b1[col];
        Hs[row * LDSTR + col] = (bf16_t)fmaxf(v, 0.f);
      }
  __syncthreads();

  // ---- GEMM2 ----
  f32x4 acc2[4][4];
  #pragma unroll
  for (int i = 0; i < 4; i++)
    #pragma unroll
    for (int j = 0; j < 4; j++) acc2[i][j] = {0.f, 0.f, 0.f, 0.f};

  #pragma unroll
  for (int kk = 0; kk < 128; kk += 32) {
    bf16x8 a[4], bb[4];
    #pragma unroll
    for (int i = 0; i < 4; i++)
      a[i] = *(const bf16x8*)&Hs[(m0 + i * 16 + ln) * LDSTR + kk + q * 8];
    #pragma unroll
    for (int j = 0; j < 4; j++)
      bb[j] = *(const bf16x8*)&W2T[(size_t)(n0 + j * 16 + ln) * 128 + kk + q * 8];
    #pragma unroll
    for (int i = 0; i < 4; i++)
      #pragma unroll
      for (int j = 0; j < 4; j++)
        acc2[i][j] = __builtin_amdgcn_mfma_f32_16x16x32_bf16(a[i], bb[j], acc2[i][j], 0, 0, 0);
  }

  // ---- +b2 into registers ----
  float b2v[4];
  #pragma unroll
  for (int j = 0; j < 4; ++j) b2v[j] = b2[n0 + j * 16 + ln];
  #pragma unroll
  for (int i = 0; i < 4; i++)
    #pragma unroll
    for (int j = 0; j < 4; j++)
      #pragma unroll
      for (int r = 0; r < 4; r++) acc2[i][j][r] += b2v[j];

  // ---- vectorized residual via f32 LDS transpose ----
  float* Ef = (float*)Hs;
  const int lr = tid >> 2;
  const int cb = (tid & 3) * 32;
  #pragma unroll
  for (int half = 0; half < 2; ++half) {
    __syncthreads();
    if (m0 == half * 64) {
      #pragma unroll
      for (int i = 0; i < 4; i++)
        #pragma unroll
        for (int j = 0; j < 4; j++)
          #pragma unroll
          for (int r = 0; r < 4; r++)
            Ef[(i * 16 + q * 4 + r) * EFSTR + n0 + j * 16 + ln] = acc2[i][j][r];
    }
    __syncthreads();
    const size_t grow = (size_t)(base + half * 64 + lr);
    if (grow < NNODES) {
      const float4* np = (const float4*)(node_f + grow * D + cb);
      float4*       op = (float4*)(out_nodes + grow * D + cb);
      #pragma unroll
      for (int t = 0; t < 8; ++t) {
        float4 n = np[t];
        float4 v = *(const float4*)&Ef[lr * EFSTR + cb + 4 * t];
        float4 o;
        o.x = n.x + v.x; o.y = n.y + v.y; o.z = n.z + v.z; o.w = n.w + v.w;
        op[t] = o;
      }
    }
  }
}

extern "C" void kernel_launch(void* const* d_in, const int* in_sizes, int n_in,
                              void* d_out, int out_size, void* d_ws, size_t ws_size,
                              hipStream_t stream) {
  const float* node_f    = (const float*)d_in[0];
  const float* edge_f    = (const float*)d_in[1];
  const int*   senders   = (const int*)d_in[2];
  const int*   receivers = (const int*)d_in[3];
  const float* We1 = (const float*)d_in[4];
  const float* be1 = (const float*)d_in[5];
  const float* We2 = (const float*)d_in[6];
  const float* be2 = (const float*)d_in[7];
  const float* Wn1 = (const float*)d_in[8];
  const float* bn1 = (const float*)d_in[9];
  const float* Wn2 = (const float*)d_in[10];
  const float* bn2 = (const float*)d_in[11];

  float* out_nodes = (float*)d_out;                       // [NNODES][128] — doubles as agg
  float* out_edges = out_nodes + (size_t)NNODES * D;      // [NEDGES][128]

  bf16_t* W1T  = (bf16_t*)d_ws;        // 128*384
  bf16_t* W2T  = W1T  + 128 * 384;     // 128*128
  bf16_t* Wn1T = W2T  + 128 * 128;     // 128*256
  bf16_t* Wn2T = Wn1T + 128 * 256;     // 128*128

  // zero the agg region (harness poisons d_out before every launch)
  hipMemsetAsync(d_out, 0, (size_t)NNODES * D * sizeof(float), stream);

  wprep_kernel<<<(384 * 128 + 255) / 256, 256, 0, stream>>>(We1, W1T, 384, 128);
  wprep_kernel<<<(128 * 128 + 255) / 256, 256, 0, stream>>>(We2, W2T, 128, 128);
  wprep_kernel<<<(256 * 128 + 255) / 256, 256, 0, stream>>>(Wn1, Wn1T, 256, 128);
  wprep_kernel<<<(128 * 128 + 255) / 256, 256, 0, stream>>>(Wn2, Wn2T, 128, 128);

  edge_kernel<<<NEDGES / 128, 256, 0, stream>>>(
      node_f, edge_f, senders, receivers, W1T, be1, W2T, be2, out_nodes, out_edges);

  node_kernel<<<(NNODES + 127) / 128, 256, 0, stream>>>(
      node_f, Wn1T, bn1, Wn2T, bn2, out_nodes, out_nodes);
}

// Round 2
// 1243.079 us; speedup vs baseline: 1.1869x; 1.1372x over previous
//
#include <hip/hip_runtime.h>
#include <hip/hip_bf16.h>
#include <stdint.h>

#define D 128
#define NNODES 100000
#define NEDGES 800000
#define LDSTR 136   // bf16 h-tile row stride (128 + 8 pad)
#define EFSTR 132   // f32 epilogue tile row stride

typedef __bf16 bf16_t;
typedef bf16_t bf16x8 __attribute__((ext_vector_type(8)));
typedef float  f32x4  __attribute__((ext_vector_type(4)));

typedef __attribute__((address_space(3))) void       lds_void;
typedef __attribute__((address_space(1))) const void glb_void;

__device__ __forceinline__ void gld_lds16(const void* g, void* l) {
  __builtin_amdgcn_global_load_lds((glb_void*)g, (lds_void*)l, 16, 0, 0);
}

// ---- weight transpose+convert: dst[n*K + k] = (bf16) src[k*N + n]
__global__ void wprep_kernel(const float* __restrict__ src, bf16_t* __restrict__ dst,
                             int K, int N) {
  int idx = blockIdx.x * blockDim.x + threadIdx.x;
  if (idx >= K * N) return;
  int n = idx / K;
  int k = idx - n * K;
  dst[idx] = (bf16_t)src[(size_t)k * N + n];
}

// ============================ EDGE KERNEL ============================
// GEMM1 K=384 split into 12 quarter-chunks (hc): sel = hc>>2 (snd|rcv|edge),
// kq = hc&3 (32-f32 K-slice). Each quarter staged ONCE per block into a 16KB
// LDS buffer via global_load_lds (3-buffer rotation, 2 phases ahead, counted
// vmcnt).  LDS layout: row-major [128 rows][8 slots of 16B], slot XOR-swizzled
// by (row&7) on BOTH the global source address and the LDS read.
__global__ __launch_bounds__(256, 3) void edge_kernel(
    const float* __restrict__ node_f, const float* __restrict__ edge_f,
    const int* __restrict__ senders, const int* __restrict__ receivers,
    const bf16_t* __restrict__ W1T,   // [128][384] bf16 (We1^T)
    const float* __restrict__ be1,
    const bf16_t* __restrict__ W2T,   // [128][128] bf16 (We2^T)
    const float* __restrict__ be2,
    float* __restrict__ agg,          // [NNODES][128] f32 (pre-zeroed)
    float* __restrict__ out_edges)    // [NEDGES][128] f32
{
  __shared__ __align__(16) char smem[49152];  // 3 x 16KB stage buffers; aliased by Hs/Ef later

  const int tid  = threadIdx.x;
  const int base = blockIdx.x * 128;
  const int lane = tid & 63;
  const int wave = tid >> 6;
  const int q    = lane >> 4;
  const int ln   = lane & 15;
  const int m0   = (wave & 1) * 64;
  const int n0   = (wave >> 1) * 64;

  // ---- staging geometry: per wave 4 instrs/phase; instr covers 8 rows x 128B
  const int sRow8 = lane >> 3;  // row within instr (0..7)
  const int slot  = lane & 7;   // 16B slot within the 128B quarter-row

  int        rowq[4];
  const float* srcSnd[4];
  const float* srcRcv[4];
  const float* srcEdg[4];
  #pragma unroll
  for (int s = 0; s < 4; ++s) {
    const int r = (wave * 4 + s) * 8 + sRow8;   // 0..127
    rowq[s]   = r;
    srcSnd[s] = node_f + (size_t)senders[base + r]   * D;
    srcRcv[s] = node_f + (size_t)receivers[base + r] * D;
    srcEdg[s] = edge_f + (size_t)(base + r)          * D;
  }

  f32x4 acc[4][4];
  #pragma unroll
  for (int i = 0; i < 4; i++)
    #pragma unroll
    for (int j = 0; j < 4; j++) acc[i][j] = {0.f, 0.f, 0.f, 0.f};

#define STAGE_E(HC) do {                                                        \
    const int sel_ = (HC) >> 2, kq_ = (HC) & 3;                                 \
    char* bufb_ = smem + ((HC) % 3) * 16384;                                    \
    _Pragma("unroll")                                                           \
    for (int s = 0; s < 4; ++s) {                                               \
      const float* srow_ = (sel_ == 0) ? srcSnd[s]                              \
                         : (sel_ == 1) ? srcRcv[s] : srcEdg[s];                 \
      const void* g_ = (const char*)srow_ + kq_ * 128                           \
                       + ((slot ^ (rowq[s] & 7)) << 4);                         \
      void* l_ = bufb_ + (wave * 4 + s) * 1024;  /* wave-uniform base */        \
      gld_lds16(g_, l_);                                                        \
    }                                                                           \
  } while (0)

#define COMPUTE_E(HC) do {                                                      \
    const int sel_ = (HC) >> 2, kq_ = (HC) & 3;                                 \
    const char* bufb_ = smem + ((HC) % 3) * 16384;                              \
    bf16x8 a_[4], bb_[4];                                                       \
    _Pragma("unroll")                                                           \
    for (int i = 0; i < 4; ++i) {                                               \
      const int r_ = m0 + i * 16 + ln;                                          \
      const int e_ = r_ & 7;                                                    \
      const char* rb_ = bufb_ + r_ * 128;                                       \
      f32x4 lo_ = *(const f32x4*)(rb_ + (((2 * q)     ^ e_) << 4));             \
      f32x4 hi_ = *(const f32x4*)(rb_ + (((2 * q + 1) ^ e_) << 4));             \
      a_[i] = (bf16x8){(bf16_t)lo_[0], (bf16_t)lo_[1], (bf16_t)lo_[2],          \
                       (bf16_t)lo_[3], (bf16_t)hi_[0], (bf16_t)hi_[1],          \
                       (bf16_t)hi_[2], (bf16_t)hi_[3]};                         \
    }                                                                           \
    const int kg_ = sel_ * 128 + kq_ * 32 + q * 8;                              \
    _Pragma("unroll")                                                           \
    for (int j = 0; j < 4; ++j)                                                 \
      bb_[j] = *(const bf16x8*)&W1T[(size_t)(n0 + j * 16 + ln) * 384 + kg_];    \
    _Pragma("unroll")                                                           \
    for (int i = 0; i < 4; ++i)                                                 \
      _Pragma("unroll")                                                         \
      for (int j = 0; j < 4; ++j)                                               \
        acc[i][j] = __builtin_amdgcn_mfma_f32_16x16x32_bf16(a_[i], bb_[j],      \
                                                            acc[i][j], 0, 0, 0);\
  } while (0)

#define PHASE_E(HC, NW) do {                                                    \
    if ((HC) + 2 < 12) STAGE_E((HC) + 2);                                       \
    asm volatile("s_waitcnt vmcnt(" #NW ")" ::: "memory");                      \
    __builtin_amdgcn_s_barrier();                                               \
    __builtin_amdgcn_sched_barrier(0);                                          \
    COMPUTE_E(HC);                                                              \
    __builtin_amdgcn_sched_barrier(0);                                          \
    __builtin_amdgcn_s_barrier();                                               \
    __builtin_amdgcn_sched_barrier(0);                                          \
  } while (0)

  // ---- GEMM1 pipeline: stage 2 ahead, counted vmcnt (4 instrs/wave/stage) ----
  STAGE_E(0);
  STAGE_E(1);
  PHASE_E(0, 8);  PHASE_E(1, 8);  PHASE_E(2, 8);  PHASE_E(3, 8);
  PHASE_E(4, 8);  PHASE_E(5, 8);  PHASE_E(6, 8);  PHASE_E(7, 8);
  PHASE_E(8, 8);  PHASE_E(9, 8);  PHASE_E(10, 4); PHASE_E(11, 0);

  // ---- h = relu(acc + be1) -> Hs (bf16, aliases stage buffers) ----
  bf16_t* Hs = (bf16_t*)smem;
  #pragma unroll
  for (int i = 0; i < 4; i++)
    #pragma unroll
    for (int j = 0; j < 4; j++)
      #pragma unroll
      for (int r = 0; r < 4; r++) {
        int row = m0 + i * 16 + q * 4 + r;
        int col = n0 + j * 16 + ln;
        float v = acc[i][j][r] + be1[col];
        Hs[row * LDSTR + col] = (bf16_t)fmaxf(v, 0.f);
      }
  __syncthreads();

  // ---- GEMM2: e_upd = h @ We2 (K=128) ----
  f32x4 acc2[4][4];
  #pragma unroll
  for (int i = 0; i < 4; i++)
    #pragma unroll
    for (int j = 0; j < 4; j++) acc2[i][j] = {0.f, 0.f, 0.f, 0.f};

  #pragma unroll
  for (int kk = 0; kk < 128; kk += 32) {
    bf16x8 a[4], bb[4];
    #pragma unroll
    for (int i = 0; i < 4; i++)
      a[i] = *(const bf16x8*)&Hs[(m0 + i * 16 + ln) * LDSTR + kk + q * 8];
    #pragma unroll
    for (int j = 0; j < 4; j++)
      bb[j] = *(const bf16x8*)&W2T[(size_t)(n0 + j * 16 + ln) * 128 + kk + q * 8];
    #pragma unroll
    for (int i = 0; i < 4; i++)
      #pragma unroll
      for (int j = 0; j < 4; j++)
        acc2[i][j] = __builtin_amdgcn_mfma_f32_16x16x32_bf16(a[i], bb[j], acc2[i][j], 0, 0, 0);
  }

  // ---- epilogue part 1: +be2, atomic scatter from register layout ----
  float be2v[4];
  #pragma unroll
  for (int j = 0; j < 4; ++j) be2v[j] = be2[n0 + j * 16 + ln];

  int rq[4][4];
  #pragma unroll
  for (int i = 0; i < 4; ++i)
    #pragma unroll
    for (int r = 0; r < 4; ++r)
      rq[i][r] = receivers[base + m0 + i * 16 + q * 4 + r];

  #pragma unroll
  for (int i = 0; i < 4; i++)
    #pragma unroll
    for (int j = 0; j < 4; j++)
      #pragma unroll
      for (int r = 0; r < 4; r++) {
        float v = acc2[i][j][r] + be2v[j];
        acc2[i][j][r] = v;
        unsafeAtomicAdd(&agg[(size_t)rq[i][r] * D + n0 + j * 16 + ln], v);
      }

  // ---- epilogue part 2: vectorized residual via f32 LDS transpose ----
  float* Ef = (float*)smem;
  const int lr = tid >> 2;          // 0..63
  const int cb = (tid & 3) * 32;    // 0,32,64,96
  #pragma unroll
  for (int half = 0; half < 2; ++half) {
    __syncthreads();
    if (m0 == half * 64) {
      #pragma unroll
      for (int i = 0; i < 4; i++)
        #pragma unroll
        for (int j = 0; j < 4; j++)
          #pragma unroll
          for (int r = 0; r < 4; r++)
            Ef[(i * 16 + q * 4 + r) * EFSTR + n0 + j * 16 + ln] = acc2[i][j][r];
    }
    __syncthreads();
    const size_t grow = (size_t)(base + half * 64 + lr);
    const float4* ep = (const float4*)(edge_f + grow * D + cb);
    float4*       op = (float4*)(out_edges + grow * D + cb);
    #pragma unroll
    for (int t = 0; t < 8; ++t) {
      float4 e = ep[t];
      float4 v = *(const float4*)&Ef[lr * EFSTR + cb + 4 * t];
      float4 o;
      o.x = e.x + v.x; o.y = e.y + v.y; o.z = e.z + v.z; o.w = e.w + v.w;
      op[t] = o;
    }
  }
#undef STAGE_E
#undef COMPUTE_E
#undef PHASE_E
}

// ============================ NODE KERNEL ============================
__global__ __launch_bounds__(256, 3) void node_kernel(
    const float* __restrict__ node_f,
    const bf16_t* __restrict__ W1T,   // [128][256] bf16 (Wn1^T)
    const float* __restrict__ b1,
    const bf16_t* __restrict__ W2T,   // [128][128] bf16 (Wn2^T)
    const float* __restrict__ b2,
    const float* __restrict__ agg,
    float* __restrict__ out_nodes)
{
  __shared__ __align__(16) bf16_t Hs[128 * LDSTR];

  const int tid    = threadIdx.x;
  const int base   = blockIdx.x * 128;
  const int nvalid = min(128, NNODES - base);

  const int lane = tid & 63;
  const int wave = tid >> 6;
  const int q    = lane >> 4;
  const int ln   = lane & 15;
  const int m0   = (wave & 1) * 64;
  const int n0   = (wave >> 1) * 64;

  const float* apA[4];
  const float* apB[4];
  #pragma unroll
  for (int i = 0; i < 4; ++i) {
    const size_t row = (size_t)(base + min(m0 + i * 16 + ln, nvalid - 1));
    apA[i] = node_f + row * D;
    apB[i] = agg    + row * D;
  }

  f32x4 acc[4][4];
  #pragma unroll
  for (int i = 0; i < 4; i++)
    #pragma unroll
    for (int j = 0; j < 4; j++) acc[i][j] = {0.f, 0.f, 0.f, 0.f};

#define MFMA_CHUNK_N(AP, CB) do {                                               \
    _Pragma("unroll")                                                           \
    for (int kk = 0; kk < 128; kk += 32) {                                      \
      bf16x8 a[4], bb[4];                                                       \
      _Pragma("unroll")                                                         \
      for (int i = 0; i < 4; ++i) {                                             \
        float4 f0 = *(const float4*)((AP)[i] + kk + q * 8);                     \
        float4 f1 = *(const float4*)((AP)[i] + kk + q * 8 + 4);                 \
        a[i] = (bf16x8){(bf16_t)f0.x, (bf16_t)f0.y, (bf16_t)f0.z, (bf16_t)f0.w,\
                        (bf16_t)f1.x, (bf16_t)f1.y, (bf16_t)f1.z, (bf16_t)f1.w};\
      }                                                                         \
      const int kg = (CB) + kk + q * 8;                                         \
      _Pragma("unroll")                                                         \
      for (int j = 0; j < 4; ++j)                                               \
        bb[j] = *(const bf16x8*)&W1T[(size_t)(n0 + j * 16 + ln) * 256 + kg];    \
      _Pragma("unroll")                                                         \
      for (int i = 0; i < 4; ++i)                                               \
        _Pragma("unroll")                                                       \
        for (int j = 0; j < 4; ++j)                                             \
          acc[i][j] = __builtin_amdgcn_mfma_f32_16x16x32_bf16(a[i], bb[j],      \
                                                              acc[i][j], 0, 0, 0);\
    }                                                                           \
  } while (0)

  MFMA_CHUNK_N(apA, 0);
  MFMA_CHUNK_N(apB, 128);

  #pragma unroll
  for (int i = 0; i < 4; i++)
    #pragma unroll
    for (int j = 0; j < 4; j++)
      #pragma unroll
      for (int r = 0; r < 4; r++) {
        int row = m0 + i * 16 + q * 4 + r;
        int col = n0 + j * 16 + ln;
        float v = acc[i][j][r] + b1[col];
        Hs[row * LDSTR + col] = (bf16_t)fmaxf(v, 0.f);
      }
  __syncthreads();

  f32x4 acc2[4][4];
  #pragma unroll
  for (int i = 0; i < 4; i++)
    #pragma unroll
    for (int j = 0; j < 4; j++) acc2[i][j] = {0.f, 0.f, 0.f, 0.f};

  #pragma unroll
  for (int kk = 0; kk < 128; kk += 32) {
    bf16x8 a[4], bb[4];
    #pragma unroll
    for (int i = 0; i < 4; i++)
      a[i] = *(const bf16x8*)&Hs[(m0 + i * 16 + ln) * LDSTR + kk + q * 8];
    #pragma unroll
    for (int j = 0; j < 4; j++)
      bb[j] = *(const bf16x8*)&W2T[(size_t)(n0 + j * 16 + ln) * 128 + kk + q * 8];
    #pragma unroll
    for (int i = 0; i < 4; i++)
      #pragma unroll
      for (int j = 0; j < 4; j++)
        acc2[i][j] = __builtin_amdgcn_mfma_f32_16x16x32_bf16(a[i], bb[j], acc2[i][j], 0, 0, 0);
  }

  float b2v[4];
  #pragma unroll
  for (int j = 0; j < 4; ++j) b2v[j] = b2[n0 + j * 16 + ln];
  #pragma unroll
  for (int i = 0; i < 4; i++)
    #pragma unroll
    for (int j = 0; j < 4; j++)
      #pragma unroll
      for (int r = 0; r < 4; r++) acc2[i][j][r] += b2v[j];

  float* Ef = (float*)Hs;
  const int lr = tid >> 2;
  const int cb = (tid & 3) * 32;
  #pragma unroll
  for (int half = 0; half < 2; ++half) {
    __syncthreads();
    if (m0 == half * 64) {
      #pragma unroll
      for (int i = 0; i < 4; i++)
        #pragma unroll
        for (int j = 0; j < 4; j++)
          #pragma unroll
          for (int r = 0; r < 4; r++)
            Ef[(i * 16 + q * 4 + r) * EFSTR + n0 + j * 16 + ln] = acc2[i][j][r];
    }
    __syncthreads();
    const size_t grow = (size_t)(base + half * 64 + lr);
    if (grow < NNODES) {
      const float4* np = (const float4*)(node_f + grow * D + cb);
      float4*       op = (float4*)(out_nodes + grow * D + cb);
      #pragma unroll
      for (int t = 0; t < 8; ++t) {
        float4 n = np[t];
        float4 v = *(const float4*)&Ef[lr * EFSTR + cb + 4 * t];
        float4 o;
        o.x = n.x + v.x; o.y = n.y + v.y; o.z = n.z + v.z; o.w = n.w + v.w;
        op[t] = o;
      }
    }
  }
#undef MFMA_CHUNK_N
}

extern "C" void kernel_launch(void* const* d_in, const int* in_sizes, int n_in,
                              void* d_out, int out_size, void* d_ws, size_t ws_size,
                              hipStream_t stream) {
  const float* node_f    = (const float*)d_in[0];
  const float* edge_f    = (const float*)d_in[1];
  const int*   senders   = (const int*)d_in[2];
  const int*   receivers = (const int*)d_in[3];
  const float* We1 = (const float*)d_in[4];
  const float* be1 = (const float*)d_in[5];
  const float* We2 = (const float*)d_in[6];
  const float* be2 = (const float*)d_in[7];
  const float* Wn1 = (const float*)d_in[8];
  const float* bn1 = (const float*)d_in[9];
  const float* Wn2 = (const float*)d_in[10];
  const float* bn2 = (const float*)d_in[11];

  float* out_nodes = (float*)d_out;                       // [NNODES][128] — doubles as agg
  float* out_edges = out_nodes + (size_t)NNODES * D;      // [NEDGES][128]

  bf16_t* W1T  = (bf16_t*)d_ws;        // 128*384
  bf16_t* W2T  = W1T  + 128 * 384;     // 128*128
  bf16_t* Wn1T = W2T  + 128 * 128;     // 128*256
  bf16_t* Wn2T = Wn1T + 128 * 256;     // 128*128

  hipMemsetAsync(d_out, 0, (size_t)NNODES * D * sizeof(float), stream);

  wprep_kernel<<<(384 * 128 + 255) / 256, 256, 0, stream>>>(We1, W1T, 384, 128);
  wprep_kernel<<<(128 * 128 + 255) / 256, 256, 0, stream>>>(We2, W2T, 128, 128);
  wprep_kernel<<<(256 * 128 + 255) / 256, 256, 0, stream>>>(Wn1, Wn1T, 256, 128);
  wprep_kernel<<<(128 * 128 + 255) / 256, 256, 0, stream>>>(Wn2, Wn2T, 128, 128);

  edge_kernel<<<NEDGES / 128, 256, 0, stream>>>(
      node_f, edge_f, senders, receivers, W1T, be1, W2T, be2, out_nodes, out_edges);

  node_kernel<<<(NNODES + 127) / 128, 256, 0, stream>>>(
      node_f, Wn1T, bn1, Wn2T, bn2, out_nodes, out_nodes);
}